// Round 1
// baseline (858.709 us; speedup 1.0000x reference)
//
#include <hip/hip_runtime.h>
#include <hip/hip_bf16.h>
#include <stdint.h>

#define Bn 16
#define Nn 8192
#define Dn 1024
#define Hn 256

typedef __attribute__((ext_vector_type(8))) short bf16x8;
typedef __attribute__((ext_vector_type(4))) float f32x4;

__device__ __forceinline__ short f2bf(float f) {
    union { float f; uint32_t u; } v; v.f = f;
    uint32_t u = v.u;
    // round-to-nearest-even fp32 -> bf16
    return (short)((u + 0x7FFFu + ((u >> 16) & 1u)) >> 16);
}

// ---------------- W1 fp32 -> bf16 pre-convert (1 MB -> 512 KB) ----------------
__global__ __launch_bounds__(256) void k_cvt_w1(const float* __restrict__ W1,
                                                short* __restrict__ w1bf) {
    int i = blockIdx.x * 256 + threadIdx.x;
    w1bf[i] = f2bf(W1[i]);
}

// ---------------- scores GEMM: X[131072,1024] x W1^T -> tanh -> dot W2 --------
// Block: 64 rows x 256 cols (all of H), 4 waves, each wave 64x64.
// LDS row stride 40 bf16 (=80B) -> conflict-free ds_read_b128 frags.
#define LSTR 40

__global__ __launch_bounds__(256) void k_scores(const float* __restrict__ X,
                                                const short* __restrict__ w1bf,
                                                const float* __restrict__ W2,
                                                float* __restrict__ scores) {
    __shared__ short xa[64 * LSTR];    // 5120 B
    __shared__ short wb[256 * LSTR];   // 20480 B
    __shared__ float sc[64];

    const int tid  = threadIdx.x;
    const int wave = tid >> 6;
    const int lane = tid & 63;
    const int quad = lane >> 4;
    const int l16  = lane & 15;

    const long row0 = (long)blockIdx.x * 64;
    const float* xbase = X + row0 * Dn;

    // X staging map: thread t loads row t>>2, k-offset (t&3)*8 (8 fp32 = 2 float4)
    const int sx_row = tid >> 2;
    const int sx_k   = (tid & 3) * 8;

    f32x4 acc[4][4];
#pragma unroll
    for (int mi = 0; mi < 4; ++mi)
#pragma unroll
        for (int ni = 0; ni < 4; ++ni)
            acc[mi][ni] = (f32x4){0.f, 0.f, 0.f, 0.f};

    for (int k0 = 0; k0 < Dn; k0 += 32) {
        // ---- stage X tile (64x32), fp32 -> bf16 in registers ----
        {
            const float* src = xbase + (long)sx_row * Dn + k0 + sx_k;
            float4 f0 = *(const float4*)(src);
            float4 f1 = *(const float4*)(src + 4);
            bf16x8 pk;
            pk[0] = f2bf(f0.x); pk[1] = f2bf(f0.y); pk[2] = f2bf(f0.z); pk[3] = f2bf(f0.w);
            pk[4] = f2bf(f1.x); pk[5] = f2bf(f1.y); pk[6] = f2bf(f1.z); pk[7] = f2bf(f1.w);
            *(bf16x8*)(&xa[sx_row * LSTR + sx_k]) = pk;
        }
        // ---- stage W1 tile (256x32) bf16, already converted ----
#pragma unroll
        for (int j = 0; j < 4; ++j) {
            int c  = tid + 256 * j;
            int r  = c >> 2;
            int kk = (c & 3) * 8;
            int4 v = *(const int4*)(w1bf + r * Dn + k0 + kk);
            *(int4*)(&wb[r * LSTR + kk]) = v;
        }
        __syncthreads();

        bf16x8 af[4], bq[4];
#pragma unroll
        for (int mi = 0; mi < 4; ++mi)
            af[mi] = *(const bf16x8*)(&xa[(mi * 16 + l16) * LSTR + quad * 8]);
#pragma unroll
        for (int ni = 0; ni < 4; ++ni)
            bq[ni] = *(const bf16x8*)(&wb[(wave * 64 + ni * 16 + l16) * LSTR + quad * 8]);
#pragma unroll
        for (int mi = 0; mi < 4; ++mi)
#pragma unroll
            for (int ni = 0; ni < 4; ++ni)
                acc[mi][ni] = __builtin_amdgcn_mfma_f32_16x16x32_bf16(af[mi], bq[ni], acc[mi][ni], 0, 0, 0);
        __syncthreads();
    }

    // ---- epilogue: score[row] = sum_h W2[h]*tanh(C[row,h]) ----
    // C/D layout: col = lane&15 (+ni*16 + wave*64), row = quad*4 + reg (+mi*16)
    if (tid < 64) sc[tid] = 0.f;
    __syncthreads();

    float w2v[4];
#pragma unroll
    for (int ni = 0; ni < 4; ++ni) w2v[ni] = W2[wave * 64 + ni * 16 + l16];

#pragma unroll
    for (int mi = 0; mi < 4; ++mi) {
#pragma unroll
        for (int r = 0; r < 4; ++r) {
            float p = 0.f;
#pragma unroll
            for (int ni = 0; ni < 4; ++ni)
                p += w2v[ni] * tanhf(acc[mi][ni][r]);
            // reduce across the 16 lanes (same rows, different cols)
            p += __shfl_xor(p, 1);
            p += __shfl_xor(p, 2);
            p += __shfl_xor(p, 4);
            p += __shfl_xor(p, 8);
            if (l16 == 0) atomicAdd(&sc[mi * 16 + quad * 4 + r], p);
        }
    }
    __syncthreads();
    if (tid < 64) scores[row0 + tid] = sc[tid];
}

// ---------------- softmax over N per batch ----------------
__global__ __launch_bounds__(256) void k_softmax(const float* __restrict__ scores,
                                                 float* __restrict__ attn) {
    const int b   = blockIdx.x;
    const int tid = threadIdx.x;
    const float* s = scores + b * Nn;
    __shared__ float red[4];
    __shared__ float red2[4];

    float m = -1e30f;
    for (int i = tid; i < Nn; i += 256) m = fmaxf(m, s[i]);
#pragma unroll
    for (int o = 32; o >= 1; o >>= 1) m = fmaxf(m, __shfl_xor(m, o));
    if ((tid & 63) == 0) red[tid >> 6] = m;
    __syncthreads();
    m = fmaxf(fmaxf(red[0], red[1]), fmaxf(red[2], red[3]));

    float sum = 0.f;
    for (int i = tid; i < Nn; i += 256) sum += expf(s[i] - m);
#pragma unroll
    for (int o = 32; o >= 1; o >>= 1) sum += __shfl_xor(sum, o);
    if ((tid & 63) == 0) red2[tid >> 6] = sum;
    __syncthreads();
    sum = red2[0] + red2[1] + red2[2] + red2[3];

    const float inv = 1.f / sum;
    float* a = attn + b * Nn;
    for (int i = tid; i < Nn; i += 256) a[i] = expf(s[i] - m) * inv;
}

// ---------------- out[b,d] = sum_n attn[b,n] * X[b,n,d] ----------------
// Grid (64 n-chunks of 128, B). Thread t owns d = 4t..4t+3 (float4, coalesced).
__global__ __launch_bounds__(256) void k_wsum(const float* __restrict__ X,
                                              const float* __restrict__ attn,
                                              float* __restrict__ out) {
    const int b   = blockIdx.y;
    const int c   = blockIdx.x;
    const int tid = threadIdx.x;
    __shared__ float a_s[128];
    if (tid < 128) a_s[tid] = attn[b * Nn + c * 128 + tid];
    __syncthreads();

    const float* xp = X + ((long)b * Nn + (long)c * 128) * Dn + tid * 4;
    float4 acc = make_float4(0.f, 0.f, 0.f, 0.f);
#pragma unroll 4
    for (int n = 0; n < 128; ++n) {
        float4 x = *(const float4*)(xp + (long)n * Dn);
        float a = a_s[n];
        acc.x += a * x.x; acc.y += a * x.y; acc.z += a * x.z; acc.w += a * x.w;
    }
    float* o = out + b * Dn + tid * 4;
    atomicAdd(o + 0, acc.x);
    atomicAdd(o + 1, acc.y);
    atomicAdd(o + 2, acc.z);
    atomicAdd(o + 3, acc.w);
}

extern "C" void kernel_launch(void* const* d_in, const int* in_sizes, int n_in,
                              void* d_out, int out_size, void* d_ws, size_t ws_size,
                              hipStream_t stream) {
    (void)in_sizes; (void)n_in; (void)ws_size;
    const float* X  = (const float*)d_in[0];
    const float* W1 = (const float*)d_in[1];
    const float* W2 = (const float*)d_in[2];
    float* out = (float*)d_out;

    char* ws = (char*)d_ws;
    short* w1bf   = (short*)ws;                              // 512 KB
    float* scores = (float*)(ws + (1 << 20));                // 512 KB
    float* attn   = (float*)(ws + (1 << 20) + (1 << 19));    // 512 KB

    hipMemsetAsync(d_out, 0, out_size * sizeof(float), stream);

    k_cvt_w1<<<(Hn * Dn) / 256, 256, 0, stream>>>(W1, w1bf);
    k_scores<<<(Bn * Nn) / 64, 256, 0, stream>>>(X, w1bf, W2, scores);
    k_softmax<<<Bn, 256, 0, stream>>>(scores, attn);
    dim3 g(64, Bn);
    k_wsum<<<g, 256, 0, stream>>>(X, attn, out);
}